// Round 1
// baseline (64.470 us; speedup 1.0000x reference)
//
#include <hip/hip_runtime.h>
#include <math.h>

// FullyConnectedVQCs via one 32x32x16 MFMA per circuit per 32 batch rows.
//
// Key algebra: every circuit's input state is a REAL product state (layer-0
// Rot is composed into the circuit matrix M~), so the imaginary input
// columns of the 32x32 real operator multiply zeros -> M_real is 32x16,
// K=16. One v_mfma_f32_32x32x16_f16 computes all 32 real output components
// (16 complex amps) for 32 batch rows at once.
//
// R8 structure (vs R7: ~23us, 2x 16x16 MFMA per 16 rows, 10 barriers):
//  - block = 32 rows x 4 waves; wave w = circuit slot w. 1024 blocks =
//    exactly 4 blocks/CU resident.
//  - per stage per wave: 4 sincos + ~30 VALU B-pack -> 1 MFMA ->
//    |amp|^2 + signed sums -> ONE shfl_xor(32) per expval.
//  - double-buffered component-major LDS H[2][16][32]: 1 barrier/stage
//    (reads of buf rb finish before barrier; next stage writes rb after).
//  - A-fragments (M_real, f16, 17x1KB) loaded straight from global (L2/L1
//    broadcast; s-loop unrolled so loads hoist).

typedef _Float16 half8 __attribute__((ext_vector_type(8)));
typedef float floatx16 __attribute__((ext_vector_type(16)));

#define N_CIRC 17
// Composed CNOT-ring permutation per SEL layer (range r=1,2,3):
// new_state[PERM[r-1][i]] = old_state[i]. Qubit q <-> bit (8>>q).
__device__ __constant__ constexpr int PERM[3][16] = {
  {0, 9, 11, 2, 15, 6, 4, 13, 7, 14, 12, 5, 8, 1, 3, 10},   // r=1
  {0, 5, 10, 15, 1, 4, 11, 14, 2, 7, 8, 13, 3, 6, 9, 12},   // r=2
  {0, 3, 6, 5, 12, 15, 10, 9, 11, 8, 13, 14, 7, 4, 1, 2},   // r=3
};

// Build M_real (32x16: real 32-dim output reps x 16 REAL input amps) for all
// 17 circuits in f16 A-fragment order for mfma_f32_32x32x16_f16:
// A[m][k]: m = lane&31, k = (lane>>5)*8 + j  (8 halves per lane).
// half index: (c*64 + ((k>>3)<<5 | m))*8 + (k&7).
// Thread (c,j) runs the gate chain on REAL basis vector e_j; column j of
// M_real is [Re a_0, Im a_0, Re a_1, Im a_1, ...] of the result.
__global__ void __launch_bounds__(64) build_M_kernel(
    const float* __restrict__ theta, _Float16* __restrict__ M) {
  int idx = blockIdx.x * 64 + threadIdx.x;
  if (idx >= N_CIRC * 16) return;
  int c = idx >> 4, j = idx & 15;
  int tt, blk;
  if (c < 4)       { tt = 0; blk = c; }
  else if (c < 8)  { tt = 3; blk = c - 4; }
  else if (c < 12) { tt = 4; blk = c - 8; }
  else if (c < 16) { tt = 1; blk = c - 12; }
  else             { tt = 2; blk = 0; }
  float sr[16], si[16];
#pragma unroll
  for (int i = 0; i < 16; ++i) { sr[i] = 0.f; si[i] = 0.f; }
  sr[j] = 1.f;
#pragma unroll
  for (int l = 0; l < 4; ++l) {
#pragma unroll
    for (int q = 0; q < 4; ++q) {
      // theta shape (5,4,4,4,3): [tt][blk][l][q][k]
      const float* th = theta + (((tt * 4 + blk) * 16) + l * 4 + q) * 3;
      float phi = th[0], the = th[1], ome = th[2];
      float st, ct;   __sincosf(0.5f * the, &st, &ct);
      float sap, cap; __sincosf(0.5f * (phi + ome), &sap, &cap);
      float sam, cam; __sincosf(0.5f * (phi - ome), &sam, &cam);
      float u00r =  cap * ct, u00i = -sap * ct;
      float u01r = -cam * st, u01i = -sam * st;
      float u10r =  cam * st, u10i = -sam * st;
      float u11r =  cap * ct, u11i =  sap * ct;
      const int m = 8 >> q;
#pragma unroll
      for (int i = 0; i < 16; ++i) {
        if (i & m) continue;
        const int i1 = i | m;
        float ar = sr[i], ai = si[i], br = sr[i1], bi = si[i1];
        sr[i]  = u00r * ar - u00i * ai + u01r * br - u01i * bi;
        si[i]  = u00r * ai + u00i * ar + u01r * bi + u01i * br;
        sr[i1] = u10r * ar - u10i * ai + u11r * br - u11i * bi;
        si[i1] = u10r * ai + u10i * ar + u11r * bi + u11i * br;
      }
    }
    const int ri = (l == 3) ? 0 : l;  // SEL ranges 1,2,3,1
    float tr[16], ti[16];
#pragma unroll
    for (int i = 0; i < 16; ++i) { tr[i] = sr[i]; ti[i] = si[i]; }
#pragma unroll
    for (int i = 0; i < 16; ++i) { sr[PERM[ri][i]] = tr[i]; si[PERM[ri][i]] = ti[i]; }
  }
#pragma unroll
  for (int m = 0; m < 32; ++m) {
    float val = (m & 1) ? si[m >> 1] : sr[m >> 1];
    int lane = ((j >> 3) << 5) | m;
    M[(size_t)(c * 64 + lane) * 8 + (j & 7)] = (_Float16)val;
  }
}

// Block = 32 batch rows x 4 waves; wave w = circuit slot w.
__global__ void __launch_bounds__(256, 4) vqc_kernel(
    const float* __restrict__ x, const _Float16* __restrict__ M,
    float* __restrict__ out, int B) {
  __shared__ float Hb[2][16][32];   // [buf][component][row] — rows hit
                                    // distinct banks; dup lanes broadcast

  const int tid  = threadIdx.x;
  const int w    = tid >> 6;          // wave = circuit slot 0..3
  const int lane = tid & 63;
  const int g = lane >> 5, n = lane & 31;  // k-group, batch-row-in-block
  const int row_base = blockIdx.x * 32;

  // load x into buf 0: H = [0, x(13), 0, 0]; consecutive tids read
  // consecutive x elements (coalesced).
  for (int i = tid; i < 32 * 13; i += 256) {
    int r = i / 13, j = i - 13 * r;
    Hb[0][1 + j][r] = (row_base + r < B) ? x[(row_base + r) * 13 + j] : 0.f;
  }
  if (tid < 32) { Hb[0][0][tid] = 0.f; Hb[0][14][tid] = 0.f; Hb[0][15][tid] = 0.f; }
  __syncthreads();

  float e_final = 0.f;

#pragma unroll
  for (int s = 0; s < 5; ++s) {
    const int rb = s & 1, wb = rb ^ 1;       // read / write buffer
    const bool active = (s < 4) || (w == 0);
    const int ci = (s < 4) ? (s * 4 + w) : 16;
    // ---- stage inputs (4 angles) for row n ----
    float x0, x1, x2, x3;
    if (s == 0) {        // 'first': contiguous block w
      x0 = Hb[rb][4 * w + 0][n]; x1 = Hb[rb][4 * w + 1][n];
      x2 = Hb[rb][4 * w + 2][n]; x3 = Hb[rb][4 * w + 3][n];
    } else if (s < 4) {  // 'multiple': x_i = E[circuit i][component w]
      x0 = Hb[rb][w][n];      x1 = Hb[rb][4 + w][n];
      x2 = Hb[rb][8 + w][n];  x3 = Hb[rb][12 + w][n];
    } else {             // final: angles = stage-3 readouts
      x0 = Hb[rb][0][n]; x1 = Hb[rb][1][n];
      x2 = Hb[rb][2][n]; x3 = Hb[rb][3][n];
    }

    float le0 = 0.f, le1 = 0.f, le2 = 0.f, le3 = 0.f;
    if (active) {
      // ---- B-fragment: real product state, lane supplies k = 8g..8g+7 ----
      // amp(k), k=b3b2b1b0: w0[b3] w1[b2] w2[b1] w3[b0]; b3 = g.
      float s0, c0, s1, c1, s2, c2, s3, c3;
      __sincosf(0.5f * x0, &s0, &c0);
      __sincosf(0.5f * x1, &s1, &c1);
      __sincosf(0.5f * x2, &s2, &c2);
      __sincosf(0.5f * x3, &s3, &c3);
      float w0 = g ? s0 : c0;
      float u0 = w0 * c1, u1 = w0 * s1;          // b2 = 0 / 1
      float w23[4] = {c2 * c3, c2 * s3, s2 * c3, s2 * s3};
      half8 bf;
#pragma unroll
      for (int t = 0; t < 8; ++t)
        bf[t] = (_Float16)(((t < 4) ? u0 : u1) * w23[t & 3]);
      // ---- one MFMA: D(32x32) = M_real(32x16) x States(16x32) ----
      half8 a = *(const half8*)&M[(size_t)(ci * 64 + lane) * 8];
      floatx16 z = {0.f,0.f,0.f,0.f,0.f,0.f,0.f,0.f,
                    0.f,0.f,0.f,0.f,0.f,0.f,0.f,0.f};
      floatx16 acc = __builtin_amdgcn_mfma_f32_32x32x16_f16(a, bf, z, 0, 0, 0);
      // D layout (measured m74/m101): col = lane&31 = n,
      // row m = (reg&3) + 8*(reg>>2) + 4*g, reg 0..15.
      // m = 2*amp + (im?), so reg qq=reg>>2, rr=reg&3:
      // amp = 4*qq + 2*g + (rr>>1), part = rr&1.
      float p[4][2];
#pragma unroll
      for (int qq = 0; qq < 4; ++qq)
#pragma unroll
        for (int h = 0; h < 2; ++h)
          p[qq][h] = acc[4 * qq + 2 * h]     * acc[4 * qq + 2 * h]
                   + acc[4 * qq + 2 * h + 1] * acc[4 * qq + 2 * h + 1];
      // amp bits: b0 = h, b1 = g, b2 = qq&1, b3 = qq>>1
      float S4[4], D4[4];
#pragma unroll
      for (int qq = 0; qq < 4; ++qq) {
        S4[qq] = p[qq][0] + p[qq][1];
        D4[qq] = p[qq][0] - p[qq][1];
      }
      le0 = (S4[0] + S4[1]) - (S4[2] + S4[3]);             // sign by b3
      le0 += __shfl_xor(le0, 32);
      if (s < 3) {
        le1 = (S4[0] - S4[1]) + (S4[2] - S4[3]);           // sign by b2
        float S = (S4[0] + S4[1]) + (S4[2] + S4[3]);
        le2 = g ? -S : S;                                  // sign by b1 = g
        le3 = (D4[0] + D4[1]) + (D4[2] + D4[3]);           // sign by b0
        le1 += __shfl_xor(le1, 32);
        le2 += __shfl_xor(le2, 32);
        le3 += __shfl_xor(le3, 32);
      }
    }
    // ---- write stage outputs to the other buffer ----
    if (s < 3) {
      if (g == 0) {      // 32 lanes, distinct banks
        Hb[wb][4 * w + 0][n] = le0; Hb[wb][4 * w + 1][n] = le1;
        Hb[wb][4 * w + 2][n] = le2; Hb[wb][4 * w + 3][n] = le3;
      }
    } else if (s == 3) {
      if (g == 0) Hb[wb][w][n] = le0;
    } else {
      e_final = le0;
    }
    __syncthreads();     // writes visible; also fences rb reads vs next writes
  }

  if (w == 0 && g == 0 && row_base + n < B) {
    const float MULT = (float)(3.141592653589793 - 1.1920928955078125e-07);
    out[row_base + n] = e_final * MULT;
  }
}

extern "C" void kernel_launch(void* const* d_in, const int* in_sizes, int n_in,
                              void* d_out, int out_size, void* d_ws, size_t ws_size,
                              hipStream_t stream) {
  const float* x     = (const float*)d_in[0];
  const float* theta = (const float*)d_in[1];
  float* out = (float*)d_out;
  _Float16* M = (_Float16*)d_ws;  // 17*64*8 halves = 17408 B
  int B = in_sizes[0] / 13;       // 32768
  hipLaunchKernelGGL(build_M_kernel, dim3((N_CIRC * 16 + 63) / 64), dim3(64),
                     0, stream, theta, M);
  int blocks = (B + 31) / 32;     // 1024 blocks x 4 waves = exactly 4/CU
  hipLaunchKernelGGL(vqc_kernel, dim3(blocks), dim3(256), 0, stream,
                     x, M, out, B);
}